// Round 1
// baseline (22027.679 us; speedup 1.0000x reference)
//
#include <hip/hip_runtime.h>
#include <math.h>

#define S_LEN 4096
#define NTAG 20
#define TAG_STOP 19
#define NEGV -10000.0f
#define NWG 16   // workgroups per LSTM direction

// ---------------- workspace layout (bytes) ----------------
// [0,256)        uint flags[64]         (flags[dir*32+wg] = steps completed by block)
// [256,8448)     float h_buf[2][2][512] (dir, parity, hid)
// [16384, +64MB) float pre[4096][4096]  (pos, row; rows 0..2047 fwd, 2048..4095 bwd)
// then           float hs[2][4096][512]
// then           float feats[4096][20]
// then           u8    bptr[4096*20]

__global__ void init_ctr(unsigned int* ctr) {
    if (threadIdx.x < 64) ctr[threadIdx.x] = 0u;
}

__device__ __forceinline__ float sigm(float x) { return 1.0f / (1.0f + expf(-x)); }

// ---------------- kernel A: embed gather + input GEMM (fp32) ----------------
// C[pos][row] = sum_k embed[sent[pos]][k] * W_cat[row][k] + (b_ih+b_hh)[row]
// BM=64 (pos) x BN=128 (row), BK=16, 256 threads, 4x8 micro-tile.
__launch_bounds__(256)
__global__ void pre_gemm(const int* __restrict__ sent, const float* __restrict__ embed,
                         const float* __restrict__ wf, const float* __restrict__ wb,
                         const float* __restrict__ bihf, const float* __restrict__ bhhf,
                         const float* __restrict__ bihb, const float* __restrict__ bhhb,
                         float* __restrict__ pre)
{
    __shared__ float As[16][68];
    __shared__ float Bs[16][136];
    __shared__ int   srow[64];
    const int tid = threadIdx.x;
    const int bm = blockIdx.x & 63;     // 64 pos-blocks
    const int bn = blockIdx.x >> 6;     // 32 row-blocks
    const int pos0 = bm * 64, row0 = bn * 128;
    if (tid < 64) srow[tid] = sent[pos0 + tid];
    __syncthreads();

    const int tx = tid & 15, ty = tid >> 4;
    float acc[4][8];
    #pragma unroll
    for (int m = 0; m < 4; ++m)
        #pragma unroll
        for (int n = 0; n < 8; ++n) acc[m][n] = 0.f;

    for (int kt = 0; kt < 1024; kt += 16) {
        {   // A tile: 64 pos x 16 k
            int m = tid >> 2, kc = (tid & 3) * 4;
            const float* src = embed + (size_t)srow[m] * 1024 + kt + kc;
            float4 v = *(const float4*)src;
            As[kc+0][m] = v.x; As[kc+1][m] = v.y; As[kc+2][m] = v.z; As[kc+3][m] = v.w;
        }
        #pragma unroll
        for (int it = 0; it < 2; ++it) {   // B tile: 128 rows x 16 k
            int n = (tid >> 2) + it * 64;
            int kc = (tid & 3) * 4;
            int grow = row0 + n;
            const float* wsrc = (grow < 2048) ? (wf + (size_t)grow * 1024)
                                              : (wb + (size_t)(grow - 2048) * 1024);
            float4 v = *(const float4*)(wsrc + kt + kc);
            Bs[kc+0][n] = v.x; Bs[kc+1][n] = v.y; Bs[kc+2][n] = v.z; Bs[kc+3][n] = v.w;
        }
        __syncthreads();
        #pragma unroll
        for (int kk = 0; kk < 16; ++kk) {
            float a[4], b[8];
            float4 av = *(const float4*)&As[kk][ty * 4];
            a[0] = av.x; a[1] = av.y; a[2] = av.z; a[3] = av.w;
            float4 bv0 = *(const float4*)&Bs[kk][tx * 8];
            float4 bv1 = *(const float4*)&Bs[kk][tx * 8 + 4];
            b[0]=bv0.x; b[1]=bv0.y; b[2]=bv0.z; b[3]=bv0.w;
            b[4]=bv1.x; b[5]=bv1.y; b[6]=bv1.z; b[7]=bv1.w;
            #pragma unroll
            for (int m = 0; m < 4; ++m)
                #pragma unroll
                for (int n = 0; n < 8; ++n) acc[m][n] += a[m] * b[n];
        }
        __syncthreads();
    }
    #pragma unroll
    for (int m = 0; m < 4; ++m) {
        int pos = pos0 + ty * 4 + m;
        #pragma unroll
        for (int n = 0; n < 8; ++n) {
            int grow = row0 + tx * 8 + n;
            float bias = (grow < 2048) ? (bihf[grow] + bhhf[grow])
                                       : (bihb[grow - 2048] + bhhb[grow - 2048]);
            pre[(size_t)pos * 4096 + grow] = acc[m][n] + bias;
        }
    }
}

// ---------------- kernel B: bidirectional LSTM, register-resident W_hh ----------------
// 32 blocks x 256 threads. blocks 0..15 = forward, 16..31 = backward.
// Each block owns 32 hidden units (128 gate rows). Thread (rg=tid>>4, ks=tid&15)
// holds rows rl=8*rg..8*rg+7 over k in [32*ks, 32*ks+32): 256 weight floats in VGPRs.
//
// Fence-free cross-block handoff: h published via relaxed AGENT atomic stores
// (sc0 sc1 write-through -> coherent at L3 when vmcnt retires; __syncthreads'
// implicit vmcnt(0) drain orders them before the per-block flag store).
// Readers use relaxed AGENT atomic loads (sc1 -> bypass stale local L2).
// No __threadfence anywhere; 'pre' stays cacheable and is prefetched 2 steps
// ahead into registers by waves 2-3 while wave 0 polls the peer flags.
__launch_bounds__(256, 1)
__global__ void lstm_kernel(const float* __restrict__ pre,
                            const float* __restrict__ w_hh_f, const float* __restrict__ w_hh_b,
                            const float* __restrict__ h0, const float* __restrict__ c0,
                            float* __restrict__ hs, float* __restrict__ h_buf,
                            unsigned int* __restrict__ flags)
{
    const int dir = blockIdx.x >> 4;
    const int wg  = blockIdx.x & 15;
    const int tid = threadIdx.x;
    const int rg  = tid >> 4;
    const int ks  = tid & 15;
    const float* w_hh = dir ? w_hh_b : w_hh_f;

    __shared__ float h_lds[576];            // 512 + pad 4 per 32
    __shared__ float pre_local[2][128];     // double-buffered, index rl = 4*jj + gate

    // load weights into registers (one-time)
    float w[8][32];
    #pragma unroll
    for (int r = 0; r < 8; ++r) {
        int rl = rg * 8 + r;                     // rl = 4*jj + gate
        int grow = (rl & 3) * 512 + wg * 32 + (rl >> 2);
        const float4* src = (const float4*)(w_hh + (size_t)grow * 512 + ks * 32);
        #pragma unroll
        for (int q = 0; q < 8; ++q) {
            float4 v = src[q];
            w[r][q*4+0] = v.x; w[r][q*4+1] = v.y; w[r][q*4+2] = v.z; w[r][q*4+3] = v.w;
        }
    }
    // cell state: ks==0 lane of each rg owns units jj=2rg, 2rg+1
    float c2[2] = {0.f, 0.f};
    if (ks == 0) {
        c2[0] = c0[dir * 512 + wg * 32 + 2 * rg];
        c2[1] = c0[dir * 512 + wg * 32 + 2 * rg + 1];
    }

    unsigned int* myflags = flags + dir * 32;

    // pre prefetch plumbing (threads 128..255 own one pre element per step)
    const int t2  = tid - 128;
    const int pg  = (t2 >= 0) ? (t2 >> 5) : 0;
    const int pjj = (t2 >= 0) ? (t2 & 31) : 0;
    const size_t pcol = (size_t)(dir * 2048 + pg * 512 + wg * 32 + pjj);
    float pre_reg = 0.f;
    if (t2 >= 0) {
        int p0 = dir ? (S_LEN - 1) : 0;
        pre_local[0][pjj * 4 + pg] = pre[(size_t)p0 * 4096 + pcol];
        int p1 = dir ? (S_LEN - 2) : 1;
        pre_reg = pre[(size_t)p1 * 4096 + pcol];
    }

    for (int s = 0; s < S_LEN; ++s) {
        const int pos = dir ? (S_LEN - 1 - s) : s;

        // ---- wait for all peers to have published step s-1 ----
        if (s > 0 && tid < NWG) {
            const unsigned int tgt = (unsigned int)s;
            while (__hip_atomic_load(&myflags[tid], __ATOMIC_RELAXED,
                                     __HIP_MEMORY_SCOPE_AGENT) < tgt) { }
        }
        __syncthreads();   // B1

        // ---- stage h_prev into LDS (2 floats per thread, 8B coherent load) ----
        {
            float hx, hy;
            const int k = 2 * tid;
            if (s == 0) {
                const float* hsrc = h0 + dir * 512;
                hx = hsrc[k]; hy = hsrc[k + 1];
            } else {
                unsigned long long u = __hip_atomic_load(
                    (unsigned long long*)&h_buf[((dir * 2) + ((s - 1) & 1)) * 512 + k],
                    __ATOMIC_RELAXED, __HIP_MEMORY_SCOPE_AGENT);
                union { unsigned long long u; float f[2]; } cv; cv.u = u;
                hx = cv.f[0]; hy = cv.f[1];
            }
            const int ki = k + ((k >> 5) << 2);
            h_lds[ki] = hx; h_lds[ki + 1] = hy;
        }
        __syncthreads();   // B2

        // ---- matvec: 8 rows x 32 k per thread ----
        float acc[8] = {0,0,0,0,0,0,0,0};
        const float* hp = &h_lds[ks * 36];
        #pragma unroll
        for (int q = 0; q < 8; ++q) {
            float4 h4 = ((const float4*)hp)[q];
            #pragma unroll
            for (int r = 0; r < 8; ++r)
                acc[r] += w[r][q*4+0]*h4.x + w[r][q*4+1]*h4.y + w[r][q*4+2]*h4.z + w[r][q*4+3]*h4.w;
        }
        // ---- reduce over the 16-lane ks group (in-wave butterfly) ----
        #pragma unroll
        for (int r = 0; r < 8; ++r) {
            acc[r] += __shfl_xor(acc[r], 1);
            acc[r] += __shfl_xor(acc[r], 2);
            acc[r] += __shfl_xor(acc[r], 4);
            acc[r] += __shfl_xor(acc[r], 8);
        }

        // ---- gates + cell update + publish (ks==0 lanes: 2 units each) ----
        if (ks == 0) {
            const float* pl = &pre_local[s & 1][rg * 8];   // rl = 8rg + r
            float hA, hB;
            {
                float gi = acc[0] + pl[0], gf = acc[1] + pl[1];
                float gg = acc[2] + pl[2], go = acc[3] + pl[3];
                float cn = sigm(gf) * c2[0] + sigm(gi) * tanhf(gg);
                hA = sigm(go) * tanhf(cn); c2[0] = cn;
            }
            {
                float gi = acc[4] + pl[4], gf = acc[5] + pl[5];
                float gg = acc[6] + pl[6], go = acc[7] + pl[7];
                float cn = sigm(gf) * c2[1] + sigm(gi) * tanhf(gg);
                hB = sigm(go) * tanhf(cn); c2[1] = cn;
            }
            const int j = wg * 32 + 2 * rg;
            union { float f[2]; unsigned long long u; } cv;
            cv.f[0] = hA; cv.f[1] = hB;
            __hip_atomic_store((unsigned long long*)&h_buf[((dir * 2) + (s & 1)) * 512 + j],
                               cv.u, __ATOMIC_RELAXED, __HIP_MEMORY_SCOPE_AGENT);
            *(float2*)&hs[((size_t)dir * S_LEN + pos) * 512 + j] = make_float2(hA, hB);
        }
        __syncthreads();   // B3 — per-wave vmcnt(0) drain: all h stores at coherence point

        if (tid == 0)      // one-way signal, fire-and-forget
            __hip_atomic_store(&myflags[wg], (unsigned int)(s + 1),
                               __ATOMIC_RELAXED, __HIP_MEMORY_SCOPE_AGENT);

        // ---- pre prefetch rotate (waves 2-3, overlaps wave-0 polling) ----
        if (t2 >= 0) {
            if (s + 1 < S_LEN) pre_local[(s + 1) & 1][pjj * 4 + pg] = pre_reg;
            if (s + 2 < S_LEN) {
                int pn = dir ? (S_LEN - 3 - s) : (s + 2);
                pre_reg = pre[(size_t)pn * 4096 + pcol];
            }
        }
    }
}

// ---------------- kernel C: feats = concat(hf,hb) @ w_out^T + b_out ----------------
__launch_bounds__(256)
__global__ void feats_kernel(const float* __restrict__ hs, const float* __restrict__ w_out,
                             const float* __restrict__ b_out, float* __restrict__ feats)
{
    const int pos = blockIdx.x;
    const int tid = threadIdx.x;
    __shared__ float hbuf[1024];
    __shared__ float red[160];
    {
        const float* hf = hs + (size_t)pos * 512;
        const float* hb = hs + ((size_t)S_LEN + pos) * 512;
        if (tid < 128) *(float4*)&hbuf[tid * 4]        = *(const float4*)&hf[tid * 4];
        else           *(float4*)&hbuf[512 + (tid-128)*4] = *(const float4*)&hb[(tid - 128) * 4];
    }
    __syncthreads();
    if (tid < 160) {
        int tag = tid >> 3, part = tid & 7;
        const float* wrow = w_out + (size_t)tag * 1024 + part * 128;
        const float* hrow = hbuf + part * 128;
        float sum = 0.f;
        #pragma unroll
        for (int q = 0; q < 32; ++q) {
            float4 a = ((const float4*)hrow)[q];
            float4 b = ((const float4*)wrow)[q];
            sum += a.x*b.x + a.y*b.y + a.z*b.z + a.w*b.w;
        }
        red[tid] = sum;
    }
    __syncthreads();
    if (tid < NTAG) {
        float sum = b_out[tid];
        #pragma unroll
        for (int p = 0; p < 8; ++p) sum += red[tid * 8 + p];
        feats[(size_t)pos * NTAG + tid] = sum;
    }
}

// ---------------- kernel D: Viterbi forward + chunked backtrace ----------------
__launch_bounds__(256)
__global__ void viterbi_kernel(const float* __restrict__ feats, const float* __restrict__ trans,
                               unsigned char* __restrict__ bptr, float* __restrict__ out)
{
    __shared__ float feat_lds[64 * NTAG];
    __shared__ int sh_best;
    __shared__ unsigned char Mmap[8][NTAG];
    __shared__ unsigned char entry_s[8];
    const int tid = threadIdx.x;

    if (tid < 64) {   // wave 0: sequential forward pass
        const int lane = tid;
        const int i = (lane < NTAG) ? lane : (NTAG - 1);
        float trow[NTAG];
        #pragma unroll
        for (int j = 0; j < NTAG; ++j) trow[j] = trans[i * NTAG + j];
        float fv[NTAG];
        #pragma unroll
        for (int j = 0; j < NTAG; ++j) fv[j] = (j == 18) ? 0.f : NEGV;

        for (int blk = 0; blk < 64; ++blk) {
            #pragma unroll
            for (int q = 0; q < 20; ++q)
                feat_lds[q * 64 + lane] = feats[blk * 1280 + q * 64 + lane];
            for (int ss = 0; ss < 64; ++ss) {
                int s = blk * 64 + ss;
                float best = fv[0] + trow[0];
                int bj = 0;
                #pragma unroll
                for (int j = 1; j < NTAG; ++j) {
                    float cand = fv[j] + trow[j];
                    if (cand > best) { best = cand; bj = j; }   // strict >: first-max tie rule
                }
                float fnew = best + feat_lds[ss * NTAG + i];
                if (lane < NTAG) bptr[s * NTAG + lane] = (unsigned char)bj;
                #pragma unroll
                for (int j = 0; j < NTAG; ++j) fv[j] = __shfl(fnew, j);
            }
        }
        if (lane == 0) {
            float best = -1e30f; int bt = 0;
            for (int j = 0; j < NTAG; ++j) {
                float t2 = fv[j] + trans[TAG_STOP * NTAG + j];
                if (t2 > best) { best = t2; bt = j; }
            }
            out[0] = best;
            sh_best = bt;
        }
    }
    __syncthreads();
    // phase 1: per-chunk entry-tag -> chunk-start-tag maps (8 chunks x 20 entries)
    if (tid < 160) {
        int c = tid / NTAG, e = tid % NTAG;
        int tag = e;
        for (int t = (c + 1) * 512 - 1; t >= c * 512; --t) tag = bptr[t * NTAG + tag];
        Mmap[c][e] = (unsigned char)tag;
    }
    __syncthreads();
    // phase 2: serial chain through 8 chunk maps
    if (tid == 0) {
        int e = sh_best;
        entry_s[7] = (unsigned char)e;
        for (int c = 7; c >= 1; --c) { e = Mmap[c][e]; entry_s[c - 1] = (unsigned char)e; }
    }
    __syncthreads();
    // phase 3: re-walk each chunk writing the path
    if (tid < 8) {
        int c = tid;
        int tag = entry_s[c];
        out[1 + (c + 1) * 512 - 1] = (float)tag;
        for (int t = (c + 1) * 512 - 1; t > c * 512; --t) {
            tag = bptr[t * NTAG + tag];
            out[1 + t - 1] = (float)tag;
        }
    }
}

extern "C" void kernel_launch(void* const* d_in, const int* in_sizes, int n_in,
                              void* d_out, int out_size, void* d_ws, size_t ws_size,
                              hipStream_t stream) {
    (void)in_sizes; (void)n_in; (void)out_size; (void)ws_size;
    const int*   sent  = (const int*)d_in[0];
    const float* embed = (const float*)d_in[1];
    const float* wihf  = (const float*)d_in[2];
    const float* whhf  = (const float*)d_in[3];
    const float* bihf  = (const float*)d_in[4];
    const float* bhhf  = (const float*)d_in[5];
    const float* wihb  = (const float*)d_in[6];
    const float* whhb  = (const float*)d_in[7];
    const float* bihb  = (const float*)d_in[8];
    const float* bhhb  = (const float*)d_in[9];
    const float* wout  = (const float*)d_in[10];
    const float* bout  = (const float*)d_in[11];
    const float* trans = (const float*)d_in[12];
    const float* h0    = (const float*)d_in[13];
    const float* c0    = (const float*)d_in[14];

    char* ws = (char*)d_ws;
    unsigned int* flags = (unsigned int*)ws;
    float* h_buf = (float*)(ws + 256);
    float* pre   = (float*)(ws + 16384);
    float* hs    = (float*)(ws + 16384 + (size_t)4096 * 4096 * 4);
    float* feats = (float*)(ws + 16384 + (size_t)4096 * 4096 * 4 + (size_t)2 * 4096 * 512 * 4);
    unsigned char* bptr = (unsigned char*)(feats + (size_t)S_LEN * NTAG);
    float* out = (float*)d_out;

    hipLaunchKernelGGL(init_ctr, dim3(1), dim3(64), 0, stream, flags);
    hipLaunchKernelGGL(pre_gemm, dim3(2048), dim3(256), 0, stream,
                       sent, embed, wihf, wihb, bihf, bhhf, bihb, bhhb, pre);
    hipLaunchKernelGGL(lstm_kernel, dim3(32), dim3(256), 0, stream,
                       pre, whhf, whhb, h0, c0, hs, h_buf, flags);
    hipLaunchKernelGGL(feats_kernel, dim3(S_LEN), dim3(256), 0, stream,
                       hs, wout, bout, feats);
    hipLaunchKernelGGL(viterbi_kernel, dim3(1), dim3(256), 0, stream,
                       feats, trans, bptr, out);
}

// Round 2
// 15857.214 us; speedup vs baseline: 1.3891x; 1.3891x over previous
//
#include <hip/hip_runtime.h>
#include <math.h>

#define S_LEN 4096
#define NTAG 20
#define TAG_STOP 19
#define NEGV -10000.0f
#define NWG 16   // workgroups per LSTM direction

// ---------------- workspace layout (bytes) ----------------
// [16384,32768)  ull h_pub[2][2][512]   (dir, parity, unit) packed {seq32|h32}
// [32768, +64MB) float pre[4096][4096]  (pos, row; rows 0..2047 fwd, 2048..4095 bwd)
// then           float hs[2][4096][512]
// then           float feats[4096][20]
// then           u8    bptr[4096*20]

__global__ void init_pub(unsigned long long* hp) {
    int i = blockIdx.x * 256 + threadIdx.x;
    if (i < 2048) hp[i] = 0ull;
}

__device__ __forceinline__ float sigm(float x) { return 1.0f / (1.0f + expf(-x)); }

// ---------------- kernel A: embed gather + input GEMM (fp32) ----------------
__launch_bounds__(256)
__global__ void pre_gemm(const int* __restrict__ sent, const float* __restrict__ embed,
                         const float* __restrict__ wf, const float* __restrict__ wb,
                         const float* __restrict__ bihf, const float* __restrict__ bhhf,
                         const float* __restrict__ bihb, const float* __restrict__ bhhb,
                         float* __restrict__ pre)
{
    __shared__ float As[16][68];
    __shared__ float Bs[16][136];
    __shared__ int   srow[64];
    const int tid = threadIdx.x;
    const int bm = blockIdx.x & 63;     // 64 pos-blocks
    const int bn = blockIdx.x >> 6;     // 32 row-blocks
    const int pos0 = bm * 64, row0 = bn * 128;
    if (tid < 64) srow[tid] = sent[pos0 + tid];
    __syncthreads();

    const int tx = tid & 15, ty = tid >> 4;
    float acc[4][8];
    #pragma unroll
    for (int m = 0; m < 4; ++m)
        #pragma unroll
        for (int n = 0; n < 8; ++n) acc[m][n] = 0.f;

    for (int kt = 0; kt < 1024; kt += 16) {
        {   // A tile: 64 pos x 16 k
            int m = tid >> 2, kc = (tid & 3) * 4;
            const float* src = embed + (size_t)srow[m] * 1024 + kt + kc;
            float4 v = *(const float4*)src;
            As[kc+0][m] = v.x; As[kc+1][m] = v.y; As[kc+2][m] = v.z; As[kc+3][m] = v.w;
        }
        #pragma unroll
        for (int it = 0; it < 2; ++it) {   // B tile: 128 rows x 16 k
            int n = (tid >> 2) + it * 64;
            int kc = (tid & 3) * 4;
            int grow = row0 + n;
            const float* wsrc = (grow < 2048) ? (wf + (size_t)grow * 1024)
                                              : (wb + (size_t)(grow - 2048) * 1024);
            float4 v = *(const float4*)(wsrc + kt + kc);
            Bs[kc+0][n] = v.x; Bs[kc+1][n] = v.y; Bs[kc+2][n] = v.z; Bs[kc+3][n] = v.w;
        }
        __syncthreads();
        #pragma unroll
        for (int kk = 0; kk < 16; ++kk) {
            float a[4], b[8];
            float4 av = *(const float4*)&As[kk][ty * 4];
            a[0] = av.x; a[1] = av.y; a[2] = av.z; a[3] = av.w;
            float4 bv0 = *(const float4*)&Bs[kk][tx * 8];
            float4 bv1 = *(const float4*)&Bs[kk][tx * 8 + 4];
            b[0]=bv0.x; b[1]=bv0.y; b[2]=bv0.z; b[3]=bv0.w;
            b[4]=bv1.x; b[5]=bv1.y; b[6]=bv1.z; b[7]=bv1.w;
            #pragma unroll
            for (int m = 0; m < 4; ++m)
                #pragma unroll
                for (int n = 0; n < 8; ++n) acc[m][n] += a[m] * b[n];
        }
        __syncthreads();
    }
    #pragma unroll
    for (int m = 0; m < 4; ++m) {
        int pos = pos0 + ty * 4 + m;
        #pragma unroll
        for (int n = 0; n < 8; ++n) {
            int grow = row0 + tx * 8 + n;
            float bias = (grow < 2048) ? (bihf[grow] + bhhf[grow])
                                       : (bihb[grow - 2048] + bhhb[grow - 2048]);
            pre[(size_t)pos * 4096 + grow] = acc[m][n] + bias;
        }
    }
}

// ---------------- kernel B: bidirectional LSTM, register-resident W_hh ----------------
// 32 blocks x 256 threads. blocks 0..15 = forward, 16..31 = backward.
// Each block owns 32 hidden units (128 gate rows). Thread (rg=tid>>4, ks=tid&15)
// holds rows rl=8*rg..8*rg+7 over k in [32*ks, 32*ks+32): 256 weight floats in regs.
//
// Cross-block handoff: the DATA IS THE FLAG. Each hidden unit published as one
// 8B agent-scope relaxed atomic {seq32 = s+1 | h32}. Readers poll their own two
// units' pairs until seq >= s (payload arrives with the observation): a single
// one-way L3 store + poll-observe per step, no flags, no fences, no vmcnt-drain
// publish barrier. Double-parity buffers; a block can only overwrite parity p
// (2 steps later) after every peer finished its staging loads of that parity
// (publishing h_{s+1} requires observing all h_s, which is published after
// B2(s), i.e. after all staging loads of h_{s-1} completed). One barrier/step:
// h_lds is double-buffered, pre_local double-buffered + 2-step reg prefetch.
__launch_bounds__(256, 1)
__global__ void lstm_kernel(const float* __restrict__ pre,
                            const float* __restrict__ w_hh_f, const float* __restrict__ w_hh_b,
                            const float* __restrict__ h0, const float* __restrict__ c0,
                            float* __restrict__ hs, unsigned long long* __restrict__ h_pub)
{
    const int dir = blockIdx.x >> 4;
    const int wg  = blockIdx.x & 15;
    const int tid = threadIdx.x;
    const int rg  = tid >> 4;
    const int ks  = tid & 15;
    const float* w_hh = dir ? w_hh_b : w_hh_f;

    __shared__ float h_lds[2][576];         // double-buffered, 512 + pad 4 per 32
    __shared__ float pre_local[2][128];     // double-buffered, index = unit*4 + gate

    // load weights into registers (one-time)
    float w[8][32];
    #pragma unroll
    for (int r = 0; r < 8; ++r) {
        int rl = rg * 8 + r;                     // rl = 4*unit_in_pair? no: gate=rl&3, unit=rl>>2
        int grow = (rl & 3) * 512 + wg * 32 + (rl >> 2);
        const float4* src = (const float4*)(w_hh + (size_t)grow * 512 + ks * 32);
        #pragma unroll
        for (int q = 0; q < 8; ++q) {
            float4 v = src[q];
            w[r][q*4+0] = v.x; w[r][q*4+1] = v.y; w[r][q*4+2] = v.z; w[r][q*4+3] = v.w;
        }
    }
    // gate lanes: ks==0 owns unit 2rg, ks==8 owns unit 2rg+1 (1 tanh chain each)
    const bool gate_lane = ((ks & 7) == 0);
    const int  unit = 2 * rg + (ks >> 3);
    float c_reg = 0.f;
    if (gate_lane) c_reg = c0[dir * 512 + wg * 32 + unit];

    unsigned long long* pub = h_pub + dir * 1024;   // [parity][512]

    // pre prefetch plumbing (threads 128..255 own one pre element per step)
    const int t2  = tid - 128;
    const int pg  = (t2 >= 0) ? (t2 >> 5) : 0;
    const int pjj = (t2 >= 0) ? (t2 & 31) : 0;
    const size_t pcol = (size_t)(dir * 2048 + pg * 512 + wg * 32 + pjj);
    float pre_reg = 0.f;
    if (t2 >= 0) {
        int p0 = dir ? (S_LEN - 1) : 0;
        pre_local[0][pjj * 4 + pg] = pre[(size_t)p0 * 4096 + pcol];
        int p1 = dir ? (S_LEN - 2) : 1;
        pre_reg = pre[(size_t)p1 * 4096 + pcol];
    }

    for (int s = 0; s < S_LEN; ++s) {
        // ---- stage h_{s-1} into h_lds[s&1]: poll own 2 units, payload = flag ----
        {
            const int k = 2 * tid;
            float hx, hy;
            if (s == 0) {
                const float* hsrc = h0 + dir * 512;
                hx = hsrc[k]; hy = hsrc[k + 1];
            } else {
                unsigned long long* p0 = &pub[(size_t)((s - 1) & 1) * 512 + k];
                const unsigned int expect = (unsigned int)s;   // written seq = (s-1)+1
                unsigned long long u0 = __hip_atomic_load(p0,     __ATOMIC_RELAXED, __HIP_MEMORY_SCOPE_AGENT);
                unsigned long long u1 = __hip_atomic_load(p0 + 1, __ATOMIC_RELAXED, __HIP_MEMORY_SCOPE_AGENT);
                while ((unsigned int)(u0 >> 32) < expect)
                    u0 = __hip_atomic_load(p0,     __ATOMIC_RELAXED, __HIP_MEMORY_SCOPE_AGENT);
                while ((unsigned int)(u1 >> 32) < expect)
                    u1 = __hip_atomic_load(p0 + 1, __ATOMIC_RELAXED, __HIP_MEMORY_SCOPE_AGENT);
                hx = __uint_as_float((unsigned int)u0);
                hy = __uint_as_float((unsigned int)u1);
            }
            const int ki = k + ((k >> 5) << 2);
            h_lds[s & 1][ki] = hx; h_lds[s & 1][ki + 1] = hy;
        }
        __syncthreads();   // the ONLY barrier per step

        // ---- matvec: 8 rows x 32 k per thread ----
        float acc[8] = {0,0,0,0,0,0,0,0};
        const float* hp = &h_lds[s & 1][ks * 36];
        #pragma unroll
        for (int q = 0; q < 8; ++q) {
            float4 h4 = ((const float4*)hp)[q];
            #pragma unroll
            for (int r = 0; r < 8; ++r)
                acc[r] += w[r][q*4+0]*h4.x + w[r][q*4+1]*h4.y + w[r][q*4+2]*h4.z + w[r][q*4+3]*h4.w;
        }
        // ---- reduce over the 16-lane ks group (in-wave butterfly) ----
        #pragma unroll
        for (int r = 0; r < 8; ++r) {
            acc[r] += __shfl_xor(acc[r], 1);
            acc[r] += __shfl_xor(acc[r], 2);
            acc[r] += __shfl_xor(acc[r], 4);
            acc[r] += __shfl_xor(acc[r], 8);
        }

        // ---- gates + cell update + publish (ks==0 and ks==8: 1 unit each) ----
        if (gate_lane) {
            const bool hiU = (ks == 8);
            const float* pl = &pre_local[s & 1][rg * 8 + (hiU ? 4 : 0)];
            float gi = (hiU ? acc[4] : acc[0]) + pl[0];
            float gf = (hiU ? acc[5] : acc[1]) + pl[1];
            float gg = (hiU ? acc[6] : acc[2]) + pl[2];
            float go = (hiU ? acc[7] : acc[3]) + pl[3];
            float cn = sigm(gf) * c_reg + sigm(gi) * tanhf(gg);
            float hN = sigm(go) * tanhf(cn);
            c_reg = cn;
            const int j = wg * 32 + unit;
            const int pos = dir ? (S_LEN - 1 - s) : s;
            hs[((size_t)dir * S_LEN + pos) * 512 + j] = hN;
            unsigned long long uv = ((unsigned long long)(unsigned int)(s + 1) << 32)
                                  | (unsigned long long)__float_as_uint(hN);
            __hip_atomic_store(&pub[(size_t)(s & 1) * 512 + j], uv,
                               __ATOMIC_RELAXED, __HIP_MEMORY_SCOPE_AGENT);
        }

        // ---- pre prefetch rotate (overlaps peers' polling) ----
        if (t2 >= 0) {
            if (s + 1 < S_LEN) pre_local[(s + 1) & 1][pjj * 4 + pg] = pre_reg;
            if (s + 2 < S_LEN) {
                int pn = dir ? (S_LEN - 3 - s) : (s + 2);
                pre_reg = pre[(size_t)pn * 4096 + pcol];
            }
        }
    }
}

// ---------------- kernel C: feats = concat(hf,hb) @ w_out^T + b_out ----------------
__launch_bounds__(256)
__global__ void feats_kernel(const float* __restrict__ hs, const float* __restrict__ w_out,
                             const float* __restrict__ b_out, float* __restrict__ feats)
{
    const int pos = blockIdx.x;
    const int tid = threadIdx.x;
    __shared__ float hbuf[1024];
    __shared__ float red[160];
    {
        const float* hf = hs + (size_t)pos * 512;
        const float* hb = hs + ((size_t)S_LEN + pos) * 512;
        if (tid < 128) *(float4*)&hbuf[tid * 4]        = *(const float4*)&hf[tid * 4];
        else           *(float4*)&hbuf[512 + (tid-128)*4] = *(const float4*)&hb[(tid - 128) * 4];
    }
    __syncthreads();
    if (tid < 160) {
        int tag = tid >> 3, part = tid & 7;
        const float* wrow = w_out + (size_t)tag * 1024 + part * 128;
        const float* hrow = hbuf + part * 128;
        float sum = 0.f;
        #pragma unroll
        for (int q = 0; q < 32; ++q) {
            float4 a = ((const float4*)hrow)[q];
            float4 b = ((const float4*)wrow)[q];
            sum += a.x*b.x + a.y*b.y + a.z*b.z + a.w*b.w;
        }
        red[tid] = sum;
    }
    __syncthreads();
    if (tid < NTAG) {
        float sum = b_out[tid];
        #pragma unroll
        for (int p = 0; p < 8; ++p) sum += red[tid * 8 + p];
        feats[(size_t)pos * NTAG + tid] = sum;
    }
}

// ---------------- kernel D: Viterbi forward + chunked backtrace ----------------
__launch_bounds__(256)
__global__ void viterbi_kernel(const float* __restrict__ feats, const float* __restrict__ trans,
                               unsigned char* __restrict__ bptr, float* __restrict__ out)
{
    __shared__ float feat_lds[64 * NTAG];
    __shared__ int sh_best;
    __shared__ unsigned char Mmap[8][NTAG];
    __shared__ unsigned char entry_s[8];
    const int tid = threadIdx.x;

    if (tid < 64) {   // wave 0: sequential forward pass
        const int lane = tid;
        const int i = (lane < NTAG) ? lane : (NTAG - 1);
        float trow[NTAG];
        #pragma unroll
        for (int j = 0; j < NTAG; ++j) trow[j] = trans[i * NTAG + j];
        float fv[NTAG];
        #pragma unroll
        for (int j = 0; j < NTAG; ++j) fv[j] = (j == 18) ? 0.f : NEGV;

        for (int blk = 0; blk < 64; ++blk) {
            #pragma unroll
            for (int q = 0; q < 20; ++q)
                feat_lds[q * 64 + lane] = feats[blk * 1280 + q * 64 + lane];
            for (int ss = 0; ss < 64; ++ss) {
                int s = blk * 64 + ss;
                float best = fv[0] + trow[0];
                int bj = 0;
                #pragma unroll
                for (int j = 1; j < NTAG; ++j) {
                    float cand = fv[j] + trow[j];
                    if (cand > best) { best = cand; bj = j; }   // strict >: first-max tie rule
                }
                float fnew = best + feat_lds[ss * NTAG + i];
                if (lane < NTAG) bptr[s * NTAG + lane] = (unsigned char)bj;
                #pragma unroll
                for (int j = 0; j < NTAG; ++j) fv[j] = __shfl(fnew, j);
            }
        }
        if (lane == 0) {
            float best = -1e30f; int bt = 0;
            for (int j = 0; j < NTAG; ++j) {
                float t2 = fv[j] + trans[TAG_STOP * NTAG + j];
                if (t2 > best) { best = t2; bt = j; }
            }
            out[0] = best;
            sh_best = bt;
        }
    }
    __syncthreads();
    // phase 1: per-chunk entry-tag -> chunk-start-tag maps (8 chunks x 20 entries)
    if (tid < 160) {
        int c = tid / NTAG, e = tid % NTAG;
        int tag = e;
        for (int t = (c + 1) * 512 - 1; t >= c * 512; --t) tag = bptr[t * NTAG + tag];
        Mmap[c][e] = (unsigned char)tag;
    }
    __syncthreads();
    // phase 2: serial chain through 8 chunk maps
    if (tid == 0) {
        int e = sh_best;
        entry_s[7] = (unsigned char)e;
        for (int c = 7; c >= 1; --c) { e = Mmap[c][e]; entry_s[c - 1] = (unsigned char)e; }
    }
    __syncthreads();
    // phase 3: re-walk each chunk writing the path
    if (tid < 8) {
        int c = tid;
        int tag = entry_s[c];
        out[1 + (c + 1) * 512 - 1] = (float)tag;
        for (int t = (c + 1) * 512 - 1; t > c * 512; --t) {
            tag = bptr[t * NTAG + tag];
            out[1 + t - 1] = (float)tag;
        }
    }
}

extern "C" void kernel_launch(void* const* d_in, const int* in_sizes, int n_in,
                              void* d_out, int out_size, void* d_ws, size_t ws_size,
                              hipStream_t stream) {
    (void)in_sizes; (void)n_in; (void)out_size; (void)ws_size;
    const int*   sent  = (const int*)d_in[0];
    const float* embed = (const float*)d_in[1];
    const float* wihf  = (const float*)d_in[2];
    const float* whhf  = (const float*)d_in[3];
    const float* bihf  = (const float*)d_in[4];
    const float* bhhf  = (const float*)d_in[5];
    const float* wihb  = (const float*)d_in[6];
    const float* whhb  = (const float*)d_in[7];
    const float* bihb  = (const float*)d_in[8];
    const float* bhhb  = (const float*)d_in[9];
    const float* wout  = (const float*)d_in[10];
    const float* bout  = (const float*)d_in[11];
    const float* trans = (const float*)d_in[12];
    const float* h0    = (const float*)d_in[13];
    const float* c0    = (const float*)d_in[14];

    char* ws = (char*)d_ws;
    unsigned long long* h_pub = (unsigned long long*)(ws + 16384);   // 16 KB: 2*2*512 pairs
    float* pre   = (float*)(ws + 32768);
    float* hs    = (float*)(ws + 32768 + (size_t)4096 * 4096 * 4);
    float* feats = (float*)(ws + 32768 + (size_t)4096 * 4096 * 4 + (size_t)2 * 4096 * 512 * 4);
    unsigned char* bptr = (unsigned char*)(feats + (size_t)S_LEN * NTAG);
    float* out = (float*)d_out;

    hipLaunchKernelGGL(init_pub, dim3(8), dim3(256), 0, stream, h_pub);
    hipLaunchKernelGGL(pre_gemm, dim3(2048), dim3(256), 0, stream,
                       sent, embed, wihf, wihb, bihf, bhhf, bihb, bhhb, pre);
    hipLaunchKernelGGL(lstm_kernel, dim3(32), dim3(256), 0, stream,
                       pre, whhf, whhb, h0, c0, hs, h_pub);
    hipLaunchKernelGGL(feats_kernel, dim3(S_LEN), dim3(256), 0, stream,
                       hs, wout, bout, feats);
    hipLaunchKernelGGL(viterbi_kernel, dim3(1), dim3(256), 0, stream,
                       feats, trans, bptr, out);
}